// Round 10
// baseline (200.028 us; speedup 1.0000x reference)
//
#include <hip/hip_runtime.h>
#include <math.h>

#define BB 4
#define NN 2048
#define KNB 30
#define HH 128
#define FFD 512

typedef __attribute__((ext_vector_type(4))) float  f32x4;
typedef __attribute__((ext_vector_type(8))) short  s16x8;
typedef __attribute__((ext_vector_type(4))) short  s16x4;

struct F3 { float x,y,z; };
__device__ __forceinline__ F3 f3(float a,float b,float c){ F3 r; r.x=a; r.y=b; r.z=c; return r; }
__device__ __forceinline__ F3 sub3(F3 a, F3 b){ return f3(a.x-b.x, a.y-b.y, a.z-b.z); }
__device__ __forceinline__ float dot3(F3 a, F3 b){ return a.x*b.x + a.y*b.y + a.z*b.z; }
__device__ __forceinline__ F3 cross3(F3 a, F3 b){
  return f3(a.y*b.z-a.z*b.y, a.z*b.x-a.x*b.z, a.x*b.y-a.y*b.x);
}
__device__ __forceinline__ F3 nrm3(F3 a){
  float n2 = dot3(a,a);
  if (n2 <= 0.f) return f3(0.f,0.f,0.f);
  float inv = 1.0f/sqrtf(n2);
  return f3(a.x*inv, a.y*inv, a.z*inv);
}
__device__ __forceinline__ float sgnf(float x){ return (x>0.f)?1.f:((x<0.f)?-1.f:0.f); }
__device__ __forceinline__ float clip1(float x){
  const float e = 1e-7f;
  return fminf(fmaxf(x, -1.f+e), 1.f-e);
}
// tanh-gelu: x * 1/(1+exp2(t*x)), t = -2.3023 - 0.10296*x^2  (folded constants)
__device__ __forceinline__ float fgelu(float x){
  float x2 = x*x;
  float t = __builtin_fmaf(-0.1029641763f, x2, -2.302344055f);
  float d = 1.f + __builtin_amdgcn_exp2f(t*x);
  return x * __builtin_amdgcn_rcpf(d);
}
// f32 -> bf16 bits, RNE
__device__ __forceinline__ short f2bf(float x){
  union { float f; unsigned u; } v; v.f = x;
  unsigned r = v.u + 0x7fffu + ((v.u >> 16) & 1u);
  return (short)(r >> 16);
}

// ---------------- K_init: geometry (blocks 0..31) + weight prep (blocks 32..808) ----------------
__global__ void k_init(const float* __restrict__ X, float* __restrict__ Qws,
                       float* __restrict__ featws,
                       const float* __restrict__ We, const float* __restrict__ Web,
                       const float* __restrict__ W1, const float* __restrict__ W2,
                       const float* __restrict__ Wi, const float* __restrict__ Wo,
                       const float* __restrict__ W3,
                       short* __restrict__ wfoldT, float* __restrict__ bfold,
                       short* __restrict__ w2t, short* __restrict__ w1aT,
                       short* __restrict__ w1cT, short* __restrict__ wiT,
                       short* __restrict__ woT, short* __restrict__ w3T){
  if (blockIdx.x < 32){
    int t = blockIdx.x*256 + threadIdx.x;     // 0..8191
    int b = t / NN, n = t % NN;
    const float* Xb = X + (size_t)b*NN*12;
    #define LD3(r,a) f3(Xb[((r)*4+(a))*3+0], Xb[((r)*4+(a))*3+1], Xb[((r)*4+(a))*3+2])
    F3 x0=LD3(n,0), x1=LD3(n,1), x2=LD3(n,2), x3=LD3(n,3);
    F3 U[5];
    U[1]=nrm3(sub3(x1,x0));
    U[2]=nrm3(sub3(x2,x1));
    if (n>0){ F3 p = LD3(n-1,2); U[0]=nrm3(sub3(x0,p)); } else U[0]=f3(0.f,0.f,0.f);
    if (n<NN-1){ F3 y0=LD3(n+1,0), y1=LD3(n+1,1); U[3]=nrm3(sub3(y0,x2)); U[4]=nrm3(sub3(y1,y0)); }
    else { U[3]=f3(0.f,0.f,0.f); U[4]=f3(0.f,0.f,0.f); }

    float feat[21];
    #pragma unroll
    for (int tt=0; tt<3; tt++){
      bool valid = (n>0 || tt>0) && (n<NN-1 || tt==0);
      if (valid){
        F3 a=U[tt], bv=U[tt+1], c=U[tt+2];
        F3 n0=nrm3(cross3(a,bv)), n1=nrm3(cross3(bv,c));
        float cd = clip1(dot3(n0,n1));
        F3 v = nrm3(cross3(n0,n1));
        float s = sgnf(-dot3(v,bv));
        feat[tt]   = (s==0.f) ? 1.f : cd;
        feat[3+tt] = s*sqrtf(fmaxf(1.f-cd*cd, 0.f));
        float ca = clip1(dot3(a,bv));
        feat[6+tt] = ca;
        feat[9+tt] = sqrtf(fmaxf(1.f-ca*ca, 0.f));
      } else {
        feat[tt]=1.f; feat[3+tt]=0.f; feat[6+tt]=1.f; feat[9+tt]=0.f;
      }
    }
    float Q[9];
    if (n<NN-1){
      F3 b1=nrm3(sub3(U[1],U[2]));
      F3 n0=nrm3(cross3(U[1],U[2]));
      F3 r2=cross3(b1,n0);
      Q[0]=b1.x;Q[1]=b1.y;Q[2]=b1.z;Q[3]=n0.x;Q[4]=n0.y;Q[5]=n0.z;Q[6]=r2.x;Q[7]=r2.y;Q[8]=r2.z;
    } else {
      #pragma unroll
      for (int i=0;i<9;i++) Q[i]=0.f;
    }
    float* qp = Qws + (size_t)t*9;
    #pragma unroll
    for (int i=0;i<9;i++) qp[i]=Q[i];

    feat[12]=0.f; feat[13]=0.f; feat[14]=0.f;
    F3 d1=sub3(x2,x0), d2=sub3(x3,x0);
    F3 r1 = nrm3(f3(Q[0]*d1.x+Q[1]*d1.y+Q[2]*d1.z,
                    Q[3]*d1.x+Q[4]*d1.y+Q[5]*d1.z,
                    Q[6]*d1.x+Q[7]*d1.y+Q[8]*d1.z));
    F3 r2v= nrm3(f3(Q[0]*d2.x+Q[1]*d2.y+Q[2]*d2.z,
                    Q[3]*d2.x+Q[4]*d2.y+Q[5]*d2.z,
                    Q[6]*d2.x+Q[7]*d2.y+Q[8]*d2.z));
    feat[15]=r1.x; feat[16]=r1.y; feat[17]=r1.z;
    feat[18]=r2v.x; feat[19]=r2v.y; feat[20]=r2v.z;
    float* fp = featws + (size_t)t*21;
    #pragma unroll
    for (int i=0;i<21;i++) fp[i]=feat[i];
    #undef LD3
    return;
  }
  int t = (blockIdx.x-32)*256 + threadIdx.x;
  if (t < 2048){
    // wfoldT[c][j] = (We @ W1mid)[j][c], bf16
    int c = t >> 4, j = t & 15;
    float a = 0.f;
    for (int k=0;k<HH;k++) a += We[j*HH+k]*W1[(HH+k)*HH + c];
    wfoldT[t] = f2bf(a);
  } else if (t < 2176){
    int c = t - 2048;
    float a = 0.f;
    for (int k=0;k<HH;k++) a += Web[k]*W1[(HH+k)*HH + c];
    bfold[c] = a;
  } else if (t < 18560){
    int i = t - 2176;  int n = i >> 7, k = i & 127;
    w2t[n*HH + k] = f2bf(W2[k*HH + n]);
  } else if (t < 34944){
    int i = t - 18560; int n = i >> 7, k = i & 127;
    w1aT[n*HH + k] = f2bf(W1[k*HH + n]);
  } else if (t < 51328){
    int i = t - 34944; int n = i >> 7, k = i & 127;
    w1cT[n*HH + k] = f2bf(W1[(256+k)*HH + n]);
  } else if (t < 116864){
    int i = t - 51328; int n = i >> 7, k = i & 127;   // n 0..511
    wiT[n*HH + k] = f2bf(Wi[k*FFD + n]);
  } else if (t < 182400){
    int i = t - 116864; int k = i >> 7, n = i & 127;  // k 0..511
    woT[n*FFD + k] = f2bf(Wo[k*HH + n]);
  } else if (t < 198784){
    int i = t - 182400; int n = i >> 7, k = i & 127;
    w3T[n*HH + k] = f2bf(W3[k*HH + n]);
  }
}

// ---- K_ep: merged edge features (blocks 0..1023) + pre S/G (blocks 1024..1279) ----
#define ENB 8
#define PNB 32
__global__ void k_ep(const float* __restrict__ X, const int* __restrict__ Eidx,
                     const float* __restrict__ Qws, short* __restrict__ efB,
                     const float* __restrict__ featws, const float* __restrict__ Wv,
                     const float* __restrict__ Wvb, const short* __restrict__ w1aT,
                     const short* __restrict__ w1cT, const float* __restrict__ W1b,
                     const float* __restrict__ bfold, float* __restrict__ hVws,
                     float* __restrict__ Sws, float* __restrict__ Gws){
  const int tid = threadIdx.x;
  if (blockIdx.x < BB*NN/ENB){
    // ---------- edge features: one thread per (node, slot) ----------
    const int nn = tid >> 5, slot = tid & 31;
    const int gnode = blockIdx.x*ENB + nn;
    const int b = gnode >> 11;
    const int n = gnode & (NN-1);
    const int bofs = b*NN;
    short out[16];
    if (slot < KNB){
      int j = Eidx[(size_t)gnode*KNB + slot];
      const float* Qs = Qws + (size_t)gnode*9;
      float q[9];
      #pragma unroll
      for (int i=0;i<9;i++) q[i]=Qs[i];
      const float* Xb = X + (size_t)b*NN*12;
      F3 Xa = f3(Xb[n*12+0], Xb[n*12+1], Xb[n*12+2]);
      const float* Xn = Xb + (size_t)j*12;
      F3 A[4];
      A[0] = f3(Xn[3],  Xn[4],  Xn[5]);
      A[1] = f3(Xn[0],  Xn[1],  Xn[2]);
      A[2] = f3(Xn[6],  Xn[7],  Xn[8]);
      A[3] = f3(Xn[9],  Xn[10], Xn[11]);
      #pragma unroll
      for (int a=0;a<4;a++){
        F3 d = sub3(A[a], Xa);
        F3 w = f3(q[0]*d.x+q[1]*d.y+q[2]*d.z,
                  q[3]*d.x+q[4]*d.y+q[5]*d.z,
                  q[6]*d.x+q[7]*d.y+q[8]*d.z);
        F3 wn = nrm3(w);
        out[a*3+0] = f2bf(wn.x);
        out[a*3+1] = f2bf(wn.y);
        out[a*3+2] = f2bf(wn.z);
      }
      const float* Qn = Qws + (size_t)(bofs + j)*9;
      float p[9];
      #pragma unroll
      for (int i=0;i<9;i++) p[i]=Qn[i];
      float R00=q[0]*p[0]+q[3]*p[3]+q[6]*p[6];
      float R01=q[0]*p[1]+q[3]*p[4]+q[6]*p[7];
      float R02=q[0]*p[2]+q[3]*p[5]+q[6]*p[8];
      float R10=q[1]*p[0]+q[4]*p[3]+q[7]*p[6];
      float R11=q[1]*p[1]+q[4]*p[4]+q[7]*p[7];
      float R12=q[1]*p[2]+q[4]*p[5]+q[7]*p[8];
      float R20=q[2]*p[0]+q[5]*p[3]+q[8]*p[6];
      float R21=q[2]*p[1]+q[5]*p[4]+q[8]*p[7];
      float R22=q[2]*p[2]+q[5]*p[5]+q[8]*p[8];
      float mx = 0.5f*sqrtf(fabsf(1.f+R00-R11-R22));
      float my = 0.5f*sqrtf(fabsf(1.f-R00+R11-R22));
      float mz = 0.5f*sqrtf(fabsf(1.f-R00-R11+R22));
      float qx = sgnf(R21-R12)*mx;
      float qy = sgnf(R02-R20)*my;
      float qz = sgnf(R10-R01)*mz;
      float qw = 0.5f*sqrtf(fmaxf(1.f+R00+R11+R22, 0.f));
      float n2 = qx*qx+qy*qy+qz*qz+qw*qw;
      float inv = (n2>0.f) ? 1.f/sqrtf(n2) : 0.f;
      out[12]=f2bf(qx*inv); out[13]=f2bf(qy*inv);
      out[14]=f2bf(qz*inv); out[15]=f2bf(qw*inv);
    } else {
      #pragma unroll
      for (int i=0;i<16;i++) out[i]=0;
    }
    short* dst = efB + ((size_t)gnode*32 + slot)*16;
    *reinterpret_cast<s16x8*>(dst)   = *reinterpret_cast<s16x8*>(&out[0]);
    *reinterpret_cast<s16x8*>(dst+8) = *reinterpret_cast<s16x8*>(&out[8]);
    return;
  }
  // ---------- pre: hV (VALU K=21); S,G (MFMA) ----------
  __shared__ __align__(16) short hvL[PNB][136];   // bf16, 272B rows
  int base = (blockIdx.x - BB*NN/ENB)*PNB;
  {
    int c = tid & 127, half = tid >> 7;
    float wv[21];
    #pragma unroll
    for (int j=0;j<21;j++) wv[j] = Wv[j*HH + c];
    float wb = Wvb[c];
    #pragma unroll 2
    for (int it=0; it<16; ++it){
      int g = it*2 + half;
      const float* f = featws + (size_t)(base+g)*21;
      float a = wb;
      #pragma unroll
      for (int j=0;j<21;j++) a += f[j]*wv[j];
      hVws[(size_t)(base+g)*HH + c] = a;
      hvL[g][c] = f2bf(a);
    }
  }
  __syncthreads();
  {
    int l = tid & 63, w = tid >> 6;
    int lr = l & 15, lg = l >> 4;
    int m = w & 1;
    int nbase = (w >> 1)*4;
    s16x8 afr[4];
    #pragma unroll
    for (int ks=0; ks<4; ks++)
      afr[ks] = *reinterpret_cast<const s16x8*>(&hvL[m*16 + lr][ks*32 + lg*8]);
    f32x4 Cs[4], Cg[4];
    #pragma unroll
    for (int q=0;q<4;q++){ Cs[q]=(f32x4){0,0,0,0}; Cg[q]=(f32x4){0,0,0,0}; }
    #pragma unroll
    for (int q=0;q<4;q++){
      int ncol = (nbase+q)*16 + lr;
      #pragma unroll
      for (int ks=0; ks<4; ks++){
        s16x8 ba = *reinterpret_cast<const s16x8*>(&w1aT[ncol*HH + ks*32 + lg*8]);
        s16x8 bc = *reinterpret_cast<const s16x8*>(&w1cT[ncol*HH + ks*32 + lg*8]);
        Cs[q] = __builtin_amdgcn_mfma_f32_16x16x32_bf16(afr[ks], ba, Cs[q], 0,0,0);
        Cg[q] = __builtin_amdgcn_mfma_f32_16x16x32_bf16(afr[ks], bc, Cg[q], 0,0,0);
      }
    }
    #pragma unroll
    for (int q=0;q<4;q++){
      int ncol = (nbase+q)*16 + lr;
      float bc = W1b[ncol] + bfold[ncol];
      #pragma unroll
      for (int i=0;i<4;i++){
        int row = m*16 + lg*4 + i;
        size_t o = (size_t)(base+row)*HH + ncol;
        Sws[o] = Cs[q][i] + bc;
        Gws[o] = Cg[q][i];
      }
    }
  }
}

// ---------------- K_msg: layer1 + layer2 (MFMA), waves independent, NO barrier ----------------
#define NPB 4            // nodes per block (one per wave)
#define A2STR 136        // bf16 row stride (272 B)
__launch_bounds__(256, 4)
__global__ void k_msg(const int* __restrict__ Eidx, const short* __restrict__ efB,
                      const float* __restrict__ Sws, const float* __restrict__ Gws,
                      const short* __restrict__ wfoldT, const short* __restrict__ w2t,
                      const float* __restrict__ W2b, float* __restrict__ csws){
  __shared__ __align__(16) short A2s[128*A2STR]; // m1 bf16; wave w owns rows [32w,32w+32)

  const int tid = threadIdx.x;
  const int gbase = blockIdx.x*NPB;
  const int b = gbase >> 11;
  const int bofs = b*NN;

  const int w  = tid >> 6;
  const int l  = tid & 63;
  const int lr = l & 15;
  const int lg = l >> 4;
  const int gnode = gbase + w;

  // ---- issue scattered gather addresses first ----
  const bool ok1 = (lr < KNB - 16);   // slot 16+lr < 30
  int j0 = Eidx[(size_t)gnode*KNB + lr];
  int j1 = ok1 ? Eidx[(size_t)gnode*KNB + 16 + lr] : 0;

  // ---- layer 1 via MFMA, TRANSPOSED: C[outcol][edge] = WfoldT @ ef^T (K=16 pad 32) ----
  {
    const float* g0 = Gws + (size_t)(bofs + j0)*HH;
    const float* g1 = Gws + (size_t)(bofs + j1)*HH;
    const float* Srow = Sws + (size_t)gnode*HH;
    s16x8 wf[8];
    #pragma unroll
    for (int ct=0; ct<8; ct++){
      if (lg < 2)
        wf[ct] = *reinterpret_cast<const s16x8*>(&wfoldT[(ct*16+lr)*16 + lg*8]);
      else
        wf[ct] = (s16x8){0,0,0,0,0,0,0,0};
    }
    const short* efn = efB + (size_t)gnode*32*16;
    s16x8 ef[2];
    #pragma unroll
    for (int rt=0; rt<2; rt++){
      if (lg < 2)
        ef[rt] = *reinterpret_cast<const s16x8*>(&efn[(rt*16 + lr)*16 + lg*8]);
      else
        ef[rt] = (s16x8){0,0,0,0,0,0,0,0};
    }
    const int e0 = w*32 + lr;
    const int e1 = e0 + 16;
    #pragma unroll
    for (int ct=0; ct<8; ct++){
      const int cbase = ct*16 + lg*4;
      f32x4 S4 = *reinterpret_cast<const f32x4*>(Srow + cbase);
      f32x4 G0 = *reinterpret_cast<const f32x4*>(g0 + cbase);
      f32x4 G1 = *reinterpret_cast<const f32x4*>(g1 + cbase);
      f32x4 C0 = __builtin_amdgcn_mfma_f32_16x16x32_bf16(wf[ct], ef[0], (f32x4){0,0,0,0}, 0,0,0);
      f32x4 C1 = __builtin_amdgcn_mfma_f32_16x16x32_bf16(wf[ct], ef[1], (f32x4){0,0,0,0}, 0,0,0);
      s16x4 o0, o1;
      #pragma unroll
      for (int i=0;i<4;i++){
        o0[i] = f2bf(fgelu(C0[i] + S4[i] + G0[i]));
        float v1 = fgelu(C1[i] + S4[i] + G1[i]);
        o1[i] = ok1 ? f2bf(v1) : (short)0;
      }
      *reinterpret_cast<s16x4*>(&A2s[e0*A2STR + cbase]) = o0;
      *reinterpret_cast<s16x4*>(&A2s[e1*A2STR + cbase]) = o1;
    }
  }
  // NO __syncthreads(): wave w reads only the A2s rows it wrote (within-wave
  // LDS ordering is enforced by compiler-inserted lgkmcnt waits).

  // ---- layer 2 (MFMA 16x16x32 bf16): wave w handles node w; colsum -> global csws ----
  {
    f32x4 Cacc[2][8];
    #pragma unroll
    for (int mt=0; mt<2; mt++)
      #pragma unroll
      for (int nt=0; nt<8; nt++)
        Cacc[mt][nt] = (f32x4){0.f,0.f,0.f,0.f};
    #pragma unroll
    for (int ks=0; ks<4; ks++){
      const int koff = ks*32 + lg*8;
      s16x8 a0 = *reinterpret_cast<const s16x8*>(&A2s[(w*32      + lr)*A2STR + koff]);
      s16x8 a1 = *reinterpret_cast<const s16x8*>(&A2s[(w*32 + 16 + lr)*A2STR + koff]);
      #pragma unroll
      for (int nt=0; nt<8; nt++){
        s16x8 bv = *reinterpret_cast<const s16x8*>(&w2t[(lr + nt*16)*HH + koff]);
        Cacc[0][nt] = __builtin_amdgcn_mfma_f32_16x16x32_bf16(a0, bv, Cacc[0][nt], 0,0,0);
        Cacc[1][nt] = __builtin_amdgcn_mfma_f32_16x16x32_bf16(a1, bv, Cacc[1][nt], 0,0,0);
      }
    }
    float* csrow = csws + (size_t)gnode*HH;
    #pragma unroll
    for (int nt=0; nt<8; nt++){
      float b2v = W2b[lr + nt*16];
      float part = 0.f;
      #pragma unroll
      for (int mt=0; mt<2; mt++){
        #pragma unroll
        for (int i=0; i<4; i++){
          int row32 = mt*16 + lg*4 + i;
          float v = fgelu(Cacc[mt][nt][i] + b2v);
          if (row32 < KNB) part += v;
        }
      }
      part += __shfl_xor(part, 16, 64);
      part += __shfl_xor(part, 32, 64);
      if (l < 16) csrow[nt*16 + lr] = part;
    }
  }
}

// ---- K4: dh GEMM + xpre + LN1 + FFN (MFMA) + LN2, 16 nodes per block, 4 waves ----
#define FNB 16
__global__ void k_ffn(const float* __restrict__ csws, const float* __restrict__ hVws,
                      const short* __restrict__ w3T, const float* __restrict__ W3b,
                      const short* __restrict__ wiT, const short* __restrict__ woT,
                      const float* __restrict__ Wib, const float* __restrict__ Wob,
                      const float* __restrict__ l1g, const float* __restrict__ l1b,
                      const float* __restrict__ l2g, const float* __restrict__ l2b,
                      float* __restrict__ out){
  __shared__ __align__(16) short hv1[FNB][136];   // cs bf16 staging, later LN1-out bf16
  __shared__ __align__(16) float yL[FNB][HH];     // f32 LN1 out (residual)
  __shared__ __align__(16) short ffh[FNB][520];   // bf16 gelu(ffn1)
  __shared__ float partS[FNB][4], partQ[FNB][4];
  const int tid = threadIdx.x;
  const int l = tid & 63, w = tid >> 6;
  const int base = blockIdx.x*FNB;
  const int lr = l & 15, lg = l >> 4;

  // ---- stage colsum -> bf16 into hv1 buffer ----
  {
    int i0 = tid*8;
    int row = i0 >> 7, col = i0 & 127;
    const float* p = csws + (size_t)(base+row)*HH + col;
    f32x4 a = *reinterpret_cast<const f32x4*>(p);
    f32x4 bq = *reinterpret_cast<const f32x4*>(p+4);
    s16x8 v;
    #pragma unroll
    for (int j=0;j<4;j++){ v[j]=f2bf(a[j]); v[4+j]=f2bf(bq[j]); }
    *reinterpret_cast<s16x8*>(&hv1[row][col]) = v;
  }
  __syncthreads();

  // ---- dh = cs @ W3 (MFMA), xpre, LN1 ----
  {
    s16x8 acs[4];
    #pragma unroll
    for (int ks=0; ks<4; ks++)
      acs[ks] = *reinterpret_cast<const s16x8*>(&hv1[lr][ks*32 + lg*8]);
    f32x4 Cd[2];
    Cd[0]=(f32x4){0,0,0,0}; Cd[1]=(f32x4){0,0,0,0};
    #pragma unroll
    for (int t2=0; t2<2; t2++){
      int ncol = (2*w+t2)*16 + lr;
      #pragma unroll
      for (int ks=0; ks<4; ks++){
        s16x8 bv = *reinterpret_cast<const s16x8*>(&w3T[ncol*HH + ks*32 + lg*8]);
        Cd[t2] = __builtin_amdgcn_mfma_f32_16x16x32_bf16(acs[ks], bv, Cd[t2], 0,0,0);
      }
    }
    float vv[2][4];
    float ps[4] = {0,0,0,0}, pq[4] = {0,0,0,0};
    #pragma unroll
    for (int t2=0; t2<2; t2++){
      int col = (2*w+t2)*16 + lr;
      float b3 = W3b[col];
      #pragma unroll
      for (int i=0;i<4;i++){
        int row = lg*4 + i;
        float v = hVws[(size_t)(base+row)*HH + col] + Cd[t2][i]*(1.f/30.f) + b3;
        vv[t2][i] = v;
        ps[i] += v; pq[i] += v*v;
      }
    }
    #pragma unroll
    for (int i=0;i<4;i++){
      #pragma unroll
      for (int o=1;o<16;o<<=1){
        ps[i] += __shfl_xor(ps[i], o, 64);
        pq[i] += __shfl_xor(pq[i], o, 64);
      }
      if (lr == 0){ partS[lg*4+i][w] = ps[i]; partQ[lg*4+i][w] = pq[i]; }
    }
    __syncthreads();
    #pragma unroll
    for (int t2=0; t2<2; t2++){
      int col = (2*w+t2)*16 + lr;
      float g1 = l1g[col], b1 = l1b[col];
      #pragma unroll
      for (int i=0;i<4;i++){
        int row = lg*4 + i;
        float S = partS[row][0]+partS[row][1]+partS[row][2]+partS[row][3];
        float Q = partQ[row][0]+partQ[row][1]+partQ[row][2]+partQ[row][3];
        float m = S*(1.f/HH);
        float inv = 1.f/sqrtf(Q*(1.f/HH) - m*m + 1e-5f);
        float y = (vv[t2][i]-m)*inv*g1 + b1;
        yL[row][col] = y;
        hv1[row][col] = f2bf(y);    // overwrites cs staging (acs already in regs, barrier passed)
      }
    }
  }
  __syncthreads();

  // ---- GEMM1: [16x128]@WiT -> gelu -> ffh bf16. wave w: N-tiles w*8..w*8+7 ----
  {
    s16x8 afr[4];
    #pragma unroll
    for (int ks=0; ks<4; ks++)
      afr[ks] = *reinterpret_cast<const s16x8*>(&hv1[lr][ks*32 + lg*8]);
    #pragma unroll
    for (int q=0; q<8; q++){
      int ncol = (w*8+q)*16 + lr;
      f32x4 C = (f32x4){0,0,0,0};
      #pragma unroll
      for (int ks=0; ks<4; ks++){
        s16x8 bv = *reinterpret_cast<const s16x8*>(&wiT[ncol*HH + ks*32 + lg*8]);
        C = __builtin_amdgcn_mfma_f32_16x16x32_bf16(afr[ks], bv, C, 0,0,0);
      }
      float bi = Wib[ncol];
      #pragma unroll
      for (int i=0;i<4;i++){
        int row = lg*4 + i;
        ffh[row][ncol] = f2bf(fgelu(C[i] + bi));
      }
    }
  }
  __syncthreads();

  // ---- GEMM2: [16x512]@WoT -> residual + LN2. wave w: N-tiles 2w, 2w+1 ----
  f32x4 C2[2];
  C2[0]=(f32x4){0,0,0,0}; C2[1]=(f32x4){0,0,0,0};
  for (int ks=0; ks<16; ++ks){
    s16x8 a = *reinterpret_cast<const s16x8*>(&ffh[lr][ks*32 + lg*8]);
    #pragma unroll
    for (int t2=0; t2<2; t2++){
      int ncol = (2*w+t2)*16 + lr;
      s16x8 bv = *reinterpret_cast<const s16x8*>(&woT[ncol*FFD + ks*32 + lg*8]);
      C2[t2] = __builtin_amdgcn_mfma_f32_16x16x32_bf16(a, bv, C2[t2], 0,0,0);
    }
  }
  float vv[2][4];
  float ps[4] = {0,0,0,0}, pq[4] = {0,0,0,0};
  #pragma unroll
  for (int t2=0; t2<2; t2++){
    int col = (2*w+t2)*16 + lr;
    float bo = Wob[col];
    #pragma unroll
    for (int i=0;i<4;i++){
      int row = lg*4 + i;
      float v = yL[row][col] + C2[t2][i] + bo;
      vv[t2][i] = v;
      ps[i] += v; pq[i] += v*v;
    }
  }
  #pragma unroll
  for (int i=0;i<4;i++){
    #pragma unroll
    for (int o=1;o<16;o<<=1){
      ps[i] += __shfl_xor(ps[i], o, 64);
      pq[i] += __shfl_xor(pq[i], o, 64);
    }
    if (lr == 0){ partS[lg*4+i][w] = ps[i]; partQ[lg*4+i][w] = pq[i]; }
  }
  __syncthreads();
  float mean[4], inv[4];
  #pragma unroll
  for (int i=0;i<4;i++){
    int row = lg*4 + i;
    float S = partS[row][0]+partS[row][1]+partS[row][2]+partS[row][3];
    float Q = partQ[row][0]+partQ[row][1]+partQ[row][2]+partQ[row][3];
    float m = S*(1.f/HH);
    float var = Q*(1.f/HH) - m*m;
    mean[i] = m;
    inv[i] = 1.f/sqrtf(var + 1e-5f);
  }
  #pragma unroll
  for (int t2=0; t2<2; t2++){
    int col = (2*w+t2)*16 + lr;
    float g2 = l2g[col], b2 = l2b[col];
    #pragma unroll
    for (int i=0;i<4;i++){
      int row = lg*4 + i;
      out[(size_t)(base+row)*HH + col] = (vv[t2][i]-mean[i])*inv[i]*g2 + b2;
    }
  }
}

extern "C" void kernel_launch(void* const* d_in, const int* in_sizes, int n_in,
                              void* d_out, int out_size, void* d_ws, size_t ws_size,
                              hipStream_t stream) {
  (void)in_sizes; (void)n_in; (void)out_size; (void)ws_size;
  const float* X   = (const float*)d_in[0];
  const int*   Ei  = (const int*)  d_in[1];
  const float* Wv  = (const float*)d_in[2];
  const float* Wvb = (const float*)d_in[3];
  const float* We  = (const float*)d_in[4];
  const float* Web = (const float*)d_in[5];
  const float* W1  = (const float*)d_in[6];
  const float* W1b = (const float*)d_in[7];
  const float* W2  = (const float*)d_in[8];
  const float* W2b = (const float*)d_in[9];
  const float* W3  = (const float*)d_in[10];
  const float* W3b = (const float*)d_in[11];
  const float* Wi  = (const float*)d_in[12];
  const float* Wib = (const float*)d_in[13];
  const float* Wo  = (const float*)d_in[14];
  const float* Wob = (const float*)d_in[15];
  const float* l1g = (const float*)d_in[16];
  const float* l1b = (const float*)d_in[17];
  const float* l2g = (const float*)d_in[18];
  const float* l2b = (const float*)d_in[19];
  float* out = (float*)d_out;

  float* wsf    = (float*)d_ws;
  float* featws = wsf + 0;        // 172032
  float* Qws    = wsf + 172032;   // 73728
  float* hVws   = wsf + 245760;   // 1048576
  float* Gws    = wsf + 1294336;  // 1048576
  float* Sws    = wsf + 2342912;  // 1048576
  float* csws   = wsf + 3391488;  // 1048576 (column sums per node)
  short* efB    = (short*)(wsf + 4440064);  // 8192*32*16 bf16 -> 2097152 floats
  short* wfoldT = (short*)(wsf + 6537216);  // 1024
  float* bfold  = wsf + 6538240;            // 128
  short* w2t    = (short*)(wsf + 6538368);  // 8192
  short* w1aT   = (short*)(wsf + 6546560);  // 8192
  short* w1cT   = (short*)(wsf + 6554752);  // 8192
  short* wiT    = (short*)(wsf + 6562944);  // 32768
  short* woT    = (short*)(wsf + 6595712);  // 32768
  short* w3T    = (short*)(wsf + 6628480);  // 8192 (end 6636672 ~26.5 MB)

  k_init<<<dim3(809), dim3(256), 0, stream>>>(X, Qws, featws, We, Web, W1, W2, Wi, Wo, W3,
                                              wfoldT, bfold, w2t, w1aT, w1cT, wiT, woT, w3T);
  k_ep  <<<dim3(BB*NN/ENB + BB*NN/PNB), dim3(256), 0, stream>>>(
            X, Ei, Qws, efB, featws, Wv, Wvb, w1aT, w1cT, W1b, bfold, hVws, Sws, Gws);
  k_msg <<<dim3(BB*NN/NPB), dim3(256), 0, stream>>>(Ei, efB, Sws, Gws,
                                                    wfoldT, w2t, W2b, csws);
  k_ffn <<<dim3(BB*NN/FNB), dim3(256), 0, stream>>>(csws, hVws, w3T, W3b, wiT, woT,
                                                    Wib, Wob, l1g, l1b, l2g, l2b, out);
}

// Round 12
// 188.078 us; speedup vs baseline: 1.0635x; 1.0635x over previous
//
#include <hip/hip_runtime.h>
#include <math.h>

#define BB 4
#define NN 2048
#define KNB 30
#define HH 128
#define FFD 512

typedef __attribute__((ext_vector_type(4))) float  f32x4;
typedef __attribute__((ext_vector_type(8))) short  s16x8;
typedef __attribute__((ext_vector_type(4))) short  s16x4;

struct F3 { float x,y,z; };
__device__ __forceinline__ F3 f3(float a,float b,float c){ F3 r; r.x=a; r.y=b; r.z=c; return r; }
__device__ __forceinline__ F3 sub3(F3 a, F3 b){ return f3(a.x-b.x, a.y-b.y, a.z-b.z); }
__device__ __forceinline__ float dot3(F3 a, F3 b){ return a.x*b.x + a.y*b.y + a.z*b.z; }
__device__ __forceinline__ F3 cross3(F3 a, F3 b){
  return f3(a.y*b.z-a.z*b.y, a.z*b.x-a.x*b.z, a.x*b.y-a.y*b.x);
}
__device__ __forceinline__ F3 nrm3(F3 a){
  float n2 = dot3(a,a);
  if (n2 <= 0.f) return f3(0.f,0.f,0.f);
  float inv = 1.0f/sqrtf(n2);
  return f3(a.x*inv, a.y*inv, a.z*inv);
}
__device__ __forceinline__ float sgnf(float x){ return (x>0.f)?1.f:((x<0.f)?-1.f:0.f); }
__device__ __forceinline__ float clip1(float x){
  const float e = 1e-7f;
  return fminf(fmaxf(x, -1.f+e), 1.f-e);
}
// tanh-gelu: x * 1/(1+exp2(t*x)), t = -2.3023 - 0.10296*x^2  (folded constants)
__device__ __forceinline__ float fgelu(float x){
  float x2 = x*x;
  float t = __builtin_fmaf(-0.1029641763f, x2, -2.302344055f);
  float d = 1.f + __builtin_amdgcn_exp2f(t*x);
  return x * __builtin_amdgcn_rcpf(d);
}
// f32 -> bf16 bits, RNE
__device__ __forceinline__ short f2bf(float x){
  union { float f; unsigned u; } v; v.f = x;
  unsigned r = v.u + 0x7fffu + ((v.u >> 16) & 1u);
  return (short)(r >> 16);
}

// ---------------- K_init: geometry (blocks 0..31) + weight prep (blocks 32..808) ----------------
__global__ void k_init(const float* __restrict__ X, float* __restrict__ Qws,
                       float* __restrict__ featws,
                       const float* __restrict__ We, const float* __restrict__ Web,
                       const float* __restrict__ W1, const float* __restrict__ W2,
                       const float* __restrict__ Wi, const float* __restrict__ Wo,
                       const float* __restrict__ W3,
                       short* __restrict__ wfoldT, float* __restrict__ bfold,
                       short* __restrict__ w2t, short* __restrict__ w1aT,
                       short* __restrict__ w1cT, short* __restrict__ wiT,
                       short* __restrict__ woT, short* __restrict__ w3T){
  if (blockIdx.x < 32){
    int t = blockIdx.x*256 + threadIdx.x;     // 0..8191
    int b = t / NN, n = t % NN;
    const float* Xb = X + (size_t)b*NN*12;
    #define LD3(r,a) f3(Xb[((r)*4+(a))*3+0], Xb[((r)*4+(a))*3+1], Xb[((r)*4+(a))*3+2])
    F3 x0=LD3(n,0), x1=LD3(n,1), x2=LD3(n,2), x3=LD3(n,3);
    F3 U[5];
    U[1]=nrm3(sub3(x1,x0));
    U[2]=nrm3(sub3(x2,x1));
    if (n>0){ F3 p = LD3(n-1,2); U[0]=nrm3(sub3(x0,p)); } else U[0]=f3(0.f,0.f,0.f);
    if (n<NN-1){ F3 y0=LD3(n+1,0), y1=LD3(n+1,1); U[3]=nrm3(sub3(y0,x2)); U[4]=nrm3(sub3(y1,y0)); }
    else { U[3]=f3(0.f,0.f,0.f); U[4]=f3(0.f,0.f,0.f); }

    float feat[21];
    #pragma unroll
    for (int tt=0; tt<3; tt++){
      bool valid = (n>0 || tt>0) && (n<NN-1 || tt==0);
      if (valid){
        F3 a=U[tt], bv=U[tt+1], c=U[tt+2];
        F3 n0=nrm3(cross3(a,bv)), n1=nrm3(cross3(bv,c));
        float cd = clip1(dot3(n0,n1));
        F3 v = nrm3(cross3(n0,n1));
        float s = sgnf(-dot3(v,bv));
        feat[tt]   = (s==0.f) ? 1.f : cd;
        feat[3+tt] = s*sqrtf(fmaxf(1.f-cd*cd, 0.f));
        float ca = clip1(dot3(a,bv));
        feat[6+tt] = ca;
        feat[9+tt] = sqrtf(fmaxf(1.f-ca*ca, 0.f));
      } else {
        feat[tt]=1.f; feat[3+tt]=0.f; feat[6+tt]=1.f; feat[9+tt]=0.f;
      }
    }
    float Q[9];
    if (n<NN-1){
      F3 b1=nrm3(sub3(U[1],U[2]));
      F3 n0=nrm3(cross3(U[1],U[2]));
      F3 r2=cross3(b1,n0);
      Q[0]=b1.x;Q[1]=b1.y;Q[2]=b1.z;Q[3]=n0.x;Q[4]=n0.y;Q[5]=n0.z;Q[6]=r2.x;Q[7]=r2.y;Q[8]=r2.z;
    } else {
      #pragma unroll
      for (int i=0;i<9;i++) Q[i]=0.f;
    }
    float* qp = Qws + (size_t)t*9;
    #pragma unroll
    for (int i=0;i<9;i++) qp[i]=Q[i];

    feat[12]=0.f; feat[13]=0.f; feat[14]=0.f;
    F3 d1=sub3(x2,x0), d2=sub3(x3,x0);
    F3 r1 = nrm3(f3(Q[0]*d1.x+Q[1]*d1.y+Q[2]*d1.z,
                    Q[3]*d1.x+Q[4]*d1.y+Q[5]*d1.z,
                    Q[6]*d1.x+Q[7]*d1.y+Q[8]*d1.z));
    F3 r2v= nrm3(f3(Q[0]*d2.x+Q[1]*d2.y+Q[2]*d2.z,
                    Q[3]*d2.x+Q[4]*d2.y+Q[5]*d2.z,
                    Q[6]*d2.x+Q[7]*d2.y+Q[8]*d2.z));
    feat[15]=r1.x; feat[16]=r1.y; feat[17]=r1.z;
    feat[18]=r2v.x; feat[19]=r2v.y; feat[20]=r2v.z;
    float* fp = featws + (size_t)t*21;
    #pragma unroll
    for (int i=0;i<21;i++) fp[i]=feat[i];
    #undef LD3
    return;
  }
  int t = (blockIdx.x-32)*256 + threadIdx.x;
  if (t < 2048){
    // wfoldT[c][j] = (We @ W1mid)[j][c], bf16
    int c = t >> 4, j = t & 15;
    float a = 0.f;
    for (int k=0;k<HH;k++) a += We[j*HH+k]*W1[(HH+k)*HH + c];
    wfoldT[t] = f2bf(a);
  } else if (t < 2176){
    int c = t - 2048;
    float a = 0.f;
    for (int k=0;k<HH;k++) a += Web[k]*W1[(HH+k)*HH + c];
    bfold[c] = a;
  } else if (t < 18560){
    int i = t - 2176;  int n = i >> 7, k = i & 127;
    w2t[n*HH + k] = f2bf(W2[k*HH + n]);
  } else if (t < 34944){
    int i = t - 18560; int n = i >> 7, k = i & 127;
    w1aT[n*HH + k] = f2bf(W1[k*HH + n]);
  } else if (t < 51328){
    int i = t - 34944; int n = i >> 7, k = i & 127;
    w1cT[n*HH + k] = f2bf(W1[(256+k)*HH + n]);
  } else if (t < 116864){
    int i = t - 51328; int n = i >> 7, k = i & 127;   // n 0..511
    wiT[n*HH + k] = f2bf(Wi[k*FFD + n]);
  } else if (t < 182400){
    int i = t - 116864; int k = i >> 7, n = i & 127;  // k 0..511
    woT[n*FFD + k] = f2bf(Wo[k*HH + n]);
  } else if (t < 198784){
    int i = t - 182400; int n = i >> 7, k = i & 127;
    w3T[n*HH + k] = f2bf(W3[k*HH + n]);
  }
}

// ---- K_ep: merged edge features (blocks 0..1023) + pre S/G (blocks 1024..1279) ----
#define ENB 8
#define PNB 32
__global__ void k_ep(const float* __restrict__ X, const int* __restrict__ Eidx,
                     const float* __restrict__ Qws, short* __restrict__ efB,
                     const float* __restrict__ featws, const float* __restrict__ Wv,
                     const float* __restrict__ Wvb, const short* __restrict__ w1aT,
                     const short* __restrict__ w1cT, const float* __restrict__ W1b,
                     const float* __restrict__ bfold, float* __restrict__ hVws,
                     float* __restrict__ Sws, float* __restrict__ Gws){
  const int tid = threadIdx.x;
  if (blockIdx.x < BB*NN/ENB){
    // ---------- edge features: one thread per (node, slot) ----------
    const int nn = tid >> 5, slot = tid & 31;
    const int gnode = blockIdx.x*ENB + nn;
    const int b = gnode >> 11;
    const int n = gnode & (NN-1);
    const int bofs = b*NN;
    short out[16];
    if (slot < KNB){
      int j = Eidx[(size_t)gnode*KNB + slot];
      const float* Qs = Qws + (size_t)gnode*9;
      float q[9];
      #pragma unroll
      for (int i=0;i<9;i++) q[i]=Qs[i];
      const float* Xb = X + (size_t)b*NN*12;
      F3 Xa = f3(Xb[n*12+0], Xb[n*12+1], Xb[n*12+2]);
      const float* Xn = Xb + (size_t)j*12;
      F3 A[4];
      A[0] = f3(Xn[3],  Xn[4],  Xn[5]);
      A[1] = f3(Xn[0],  Xn[1],  Xn[2]);
      A[2] = f3(Xn[6],  Xn[7],  Xn[8]);
      A[3] = f3(Xn[9],  Xn[10], Xn[11]);
      #pragma unroll
      for (int a=0;a<4;a++){
        F3 d = sub3(A[a], Xa);
        F3 w = f3(q[0]*d.x+q[1]*d.y+q[2]*d.z,
                  q[3]*d.x+q[4]*d.y+q[5]*d.z,
                  q[6]*d.x+q[7]*d.y+q[8]*d.z);
        F3 wn = nrm3(w);
        out[a*3+0] = f2bf(wn.x);
        out[a*3+1] = f2bf(wn.y);
        out[a*3+2] = f2bf(wn.z);
      }
      const float* Qn = Qws + (size_t)(bofs + j)*9;
      float p[9];
      #pragma unroll
      for (int i=0;i<9;i++) p[i]=Qn[i];
      float R00=q[0]*p[0]+q[3]*p[3]+q[6]*p[6];
      float R01=q[0]*p[1]+q[3]*p[4]+q[6]*p[7];
      float R02=q[0]*p[2]+q[3]*p[5]+q[6]*p[8];
      float R10=q[1]*p[0]+q[4]*p[3]+q[7]*p[6];
      float R11=q[1]*p[1]+q[4]*p[4]+q[7]*p[7];
      float R12=q[1]*p[2]+q[4]*p[5]+q[7]*p[8];
      float R20=q[2]*p[0]+q[5]*p[3]+q[8]*p[6];
      float R21=q[2]*p[1]+q[5]*p[4]+q[8]*p[7];
      float R22=q[2]*p[2]+q[5]*p[5]+q[8]*p[8];
      float mx = 0.5f*sqrtf(fabsf(1.f+R00-R11-R22));
      float my = 0.5f*sqrtf(fabsf(1.f-R00+R11-R22));
      float mz = 0.5f*sqrtf(fabsf(1.f-R00-R11+R22));
      float qx = sgnf(R21-R12)*mx;
      float qy = sgnf(R02-R20)*my;
      float qz = sgnf(R10-R01)*mz;
      float qw = 0.5f*sqrtf(fmaxf(1.f+R00+R11+R22, 0.f));
      float n2 = qx*qx+qy*qy+qz*qz+qw*qw;
      float inv = (n2>0.f) ? 1.f/sqrtf(n2) : 0.f;
      out[12]=f2bf(qx*inv); out[13]=f2bf(qy*inv);
      out[14]=f2bf(qz*inv); out[15]=f2bf(qw*inv);
    } else {
      #pragma unroll
      for (int i=0;i<16;i++) out[i]=0;
    }
    short* dst = efB + ((size_t)gnode*32 + slot)*16;
    *reinterpret_cast<s16x8*>(dst)   = *reinterpret_cast<s16x8*>(&out[0]);
    *reinterpret_cast<s16x8*>(dst+8) = *reinterpret_cast<s16x8*>(&out[8]);
    return;
  }
  // ---------- pre: hV (VALU K=21); S,G (MFMA) ----------
  __shared__ __align__(16) short hvL[PNB][136];   // bf16, 272B rows
  int base = (blockIdx.x - BB*NN/ENB)*PNB;
  {
    int c = tid & 127, half = tid >> 7;
    float wv[21];
    #pragma unroll
    for (int j=0;j<21;j++) wv[j] = Wv[j*HH + c];
    float wb = Wvb[c];
    #pragma unroll 2
    for (int it=0; it<16; ++it){
      int g = it*2 + half;
      const float* f = featws + (size_t)(base+g)*21;
      float a = wb;
      #pragma unroll
      for (int j=0;j<21;j++) a += f[j]*wv[j];
      hVws[(size_t)(base+g)*HH + c] = a;
      hvL[g][c] = f2bf(a);
    }
  }
  __syncthreads();
  {
    int l = tid & 63, w = tid >> 6;
    int lr = l & 15, lg = l >> 4;
    int m = w & 1;
    int nbase = (w >> 1)*4;
    s16x8 afr[4];
    #pragma unroll
    for (int ks=0; ks<4; ks++)
      afr[ks] = *reinterpret_cast<const s16x8*>(&hvL[m*16 + lr][ks*32 + lg*8]);
    f32x4 Cs[4], Cg[4];
    #pragma unroll
    for (int q=0;q<4;q++){ Cs[q]=(f32x4){0,0,0,0}; Cg[q]=(f32x4){0,0,0,0}; }
    #pragma unroll
    for (int q=0;q<4;q++){
      int ncol = (nbase+q)*16 + lr;
      #pragma unroll
      for (int ks=0; ks<4; ks++){
        s16x8 ba = *reinterpret_cast<const s16x8*>(&w1aT[ncol*HH + ks*32 + lg*8]);
        s16x8 bc = *reinterpret_cast<const s16x8*>(&w1cT[ncol*HH + ks*32 + lg*8]);
        Cs[q] = __builtin_amdgcn_mfma_f32_16x16x32_bf16(afr[ks], ba, Cs[q], 0,0,0);
        Cg[q] = __builtin_amdgcn_mfma_f32_16x16x32_bf16(afr[ks], bc, Cg[q], 0,0,0);
      }
    }
    #pragma unroll
    for (int q=0;q<4;q++){
      int ncol = (nbase+q)*16 + lr;
      float bc = W1b[ncol] + bfold[ncol];
      #pragma unroll
      for (int i=0;i<4;i++){
        int row = m*16 + lg*4 + i;
        size_t o = (size_t)(base+row)*HH + ncol;
        Sws[o] = Cs[q][i] + bc;
        Gws[o] = Cg[q][i];
      }
    }
  }
}

// ---- K_fused: msg (4 groups x 4 nodes) + dh GEMM + LN1 + FFN + LN2, 16 nodes/block ----
#define FNB 16
#define A2STR 136        // bf16 row stride (272 B)
__launch_bounds__(256, 2)
__global__ void k_fused(const int* __restrict__ Eidx, const short* __restrict__ efB,
                        const float* __restrict__ Sws, const float* __restrict__ Gws,
                        const short* __restrict__ wfoldT, const short* __restrict__ w2t,
                        const float* __restrict__ W2b,
                        const float* __restrict__ hVws,
                        const short* __restrict__ w3T, const float* __restrict__ W3b,
                        const short* __restrict__ wiT, const short* __restrict__ woT,
                        const float* __restrict__ Wib, const float* __restrict__ Wob,
                        const float* __restrict__ l1g, const float* __restrict__ l1b,
                        const float* __restrict__ l2g, const float* __restrict__ l2b,
                        float* __restrict__ out){
  __shared__ __align__(16) short A2s[128*A2STR];  // 34816 B; reused by ffn buffers
  __shared__ __align__(16) float csL[FNB][HH];    // 8192 B
  __shared__ float partS[FNB][4], partQ[FNB][4];
  // ffn aliases into A2s (dead after msg loop):
  short* hv1b = A2s;                        // [16][136] bf16, 4352 B
  float* yLb  = (float*)(A2s + 2176);       // [16][128] f32,  8192 B
  short* ffhb = A2s + 6272;                 // [16][520] bf16, 16640 B (total 29184 <= 34816)

  const int tid = threadIdx.x;
  const int base = blockIdx.x*FNB;
  const int b = base >> 11;
  const int bofs = b*NN;
  const int w  = tid >> 6;
  const int l  = tid & 63;
  const int lr = l & 15;
  const int lg = l >> 4;

  // ---- wfold A-frags: invariant across groups ----
  s16x8 wf[8];
  #pragma unroll
  for (int ct=0; ct<8; ct++){
    if (lg < 2)
      wf[ct] = *reinterpret_cast<const s16x8*>(&wfoldT[(ct*16+lr)*16 + lg*8]);
    else
      wf[ct] = (s16x8){0,0,0,0,0,0,0,0};
  }
  const bool ok1 = (lr < KNB - 16);

  // ================= MSG: 4 groups of 4 nodes (wave w -> node g*4+w) =================
  for (int g=0; g<4; ++g){
    const int ln = g*4 + w;                 // local node 0..15
    const int gnode = base + ln;
    // layer 1: C[outcol][edge] = WfoldT @ ef^T (K=16 pad 32)
    {
      int j0 = Eidx[(size_t)gnode*KNB + lr];
      int j1 = ok1 ? Eidx[(size_t)gnode*KNB + 16 + lr] : 0;
      const float* g0 = Gws + (size_t)(bofs + j0)*HH;
      const float* g1 = Gws + (size_t)(bofs + j1)*HH;
      const float* Srow = Sws + (size_t)gnode*HH;
      const short* efn = efB + (size_t)gnode*32*16;
      s16x8 ef[2];
      #pragma unroll
      for (int rt=0; rt<2; rt++){
        if (lg < 2)
          ef[rt] = *reinterpret_cast<const s16x8*>(&efn[(rt*16 + lr)*16 + lg*8]);
        else
          ef[rt] = (s16x8){0,0,0,0,0,0,0,0};
      }
      const int e0 = w*32 + lr;
      const int e1 = e0 + 16;
      #pragma unroll
      for (int ct=0; ct<8; ct++){
        const int cbase = ct*16 + lg*4;
        f32x4 S4 = *reinterpret_cast<const f32x4*>(Srow + cbase);
        f32x4 G0 = *reinterpret_cast<const f32x4*>(g0 + cbase);
        f32x4 G1 = *reinterpret_cast<const f32x4*>(g1 + cbase);
        f32x4 C0 = __builtin_amdgcn_mfma_f32_16x16x32_bf16(wf[ct], ef[0], (f32x4){0,0,0,0}, 0,0,0);
        f32x4 C1 = __builtin_amdgcn_mfma_f32_16x16x32_bf16(wf[ct], ef[1], (f32x4){0,0,0,0}, 0,0,0);
        s16x4 o0, o1;
        #pragma unroll
        for (int i=0;i<4;i++){
          o0[i] = f2bf(fgelu(C0[i] + S4[i] + G0[i]));
          float v1 = fgelu(C1[i] + S4[i] + G1[i]);
          o1[i] = ok1 ? f2bf(v1) : (short)0;
        }
        *reinterpret_cast<s16x4*>(&A2s[e0*A2STR + cbase]) = o0;
        *reinterpret_cast<s16x4*>(&A2s[e1*A2STR + cbase]) = o1;
      }
    }
    __syncthreads();
    // layer 2: m2 colsum -> csL[ln]
    {
      f32x4 Cacc[2][8];
      #pragma unroll
      for (int mt=0; mt<2; mt++)
        #pragma unroll
        for (int nt=0; nt<8; nt++)
          Cacc[mt][nt] = (f32x4){0.f,0.f,0.f,0.f};
      #pragma unroll
      for (int ks=0; ks<4; ks++){
        const int koff = ks*32 + lg*8;
        s16x8 a0 = *reinterpret_cast<const s16x8*>(&A2s[(w*32      + lr)*A2STR + koff]);
        s16x8 a1 = *reinterpret_cast<const s16x8*>(&A2s[(w*32 + 16 + lr)*A2STR + koff]);
        #pragma unroll
        for (int nt=0; nt<8; nt++){
          s16x8 bv = *reinterpret_cast<const s16x8*>(&w2t[(lr + nt*16)*HH + koff]);
          Cacc[0][nt] = __builtin_amdgcn_mfma_f32_16x16x32_bf16(a0, bv, Cacc[0][nt], 0,0,0);
          Cacc[1][nt] = __builtin_amdgcn_mfma_f32_16x16x32_bf16(a1, bv, Cacc[1][nt], 0,0,0);
        }
      }
      #pragma unroll
      for (int nt=0; nt<8; nt++){
        float b2v = W2b[lr + nt*16];
        float part = 0.f;
        #pragma unroll
        for (int mt=0; mt<2; mt++){
          #pragma unroll
          for (int i=0; i<4; i++){
            int row32 = mt*16 + lg*4 + i;
            float v = fgelu(Cacc[mt][nt][i] + b2v);
            if (row32 < KNB) part += v;
          }
        }
        part += __shfl_xor(part, 16, 64);
        part += __shfl_xor(part, 32, 64);
        if (l < 16) csL[ln][nt*16 + lr] = part;
      }
    }
    __syncthreads();
  }

  // ================= FFN (A2s region now dead; reuse as hv1/yL/ffh) =================
  // ---- stage colsum -> bf16 into hv1 ----
  {
    int i0 = tid*8;
    int row = i0 >> 7, col = i0 & 127;
    const float* p = &csL[row][col];
    s16x8 v;
    #pragma unroll
    for (int j=0;j<8;j++) v[j] = f2bf(p[j]);
    *reinterpret_cast<s16x8*>(&hv1b[row*136 + col]) = v;
  }
  __syncthreads();

  // ---- dh = cs @ W3 (MFMA), xpre, LN1 ----
  {
    s16x8 acs[4];
    #pragma unroll
    for (int ks=0; ks<4; ks++)
      acs[ks] = *reinterpret_cast<const s16x8*>(&hv1b[lr*136 + ks*32 + lg*8]);
    f32x4 Cd[2];
    Cd[0]=(f32x4){0,0,0,0}; Cd[1]=(f32x4){0,0,0,0};
    #pragma unroll
    for (int t2=0; t2<2; t2++){
      int ncol = (2*w+t2)*16 + lr;
      #pragma unroll
      for (int ks=0; ks<4; ks++){
        s16x8 bv = *reinterpret_cast<const s16x8*>(&w3T[ncol*HH + ks*32 + lg*8]);
        Cd[t2] = __builtin_amdgcn_mfma_f32_16x16x32_bf16(acs[ks], bv, Cd[t2], 0,0,0);
      }
    }
    float vv[2][4];
    float ps[4] = {0,0,0,0}, pq[4] = {0,0,0,0};
    #pragma unroll
    for (int t2=0; t2<2; t2++){
      int col = (2*w+t2)*16 + lr;
      float b3 = W3b[col];
      #pragma unroll
      for (int i=0;i<4;i++){
        int row = lg*4 + i;
        float v = hVws[(size_t)(base+row)*HH + col] + Cd[t2][i]*(1.f/30.f) + b3;
        vv[t2][i] = v;
        ps[i] += v; pq[i] += v*v;
      }
    }
    #pragma unroll
    for (int i=0;i<4;i++){
      #pragma unroll
      for (int o=1;o<16;o<<=1){
        ps[i] += __shfl_xor(ps[i], o, 64);
        pq[i] += __shfl_xor(pq[i], o, 64);
      }
      if (lr == 0){ partS[lg*4+i][w] = ps[i]; partQ[lg*4+i][w] = pq[i]; }
    }
    __syncthreads();
    #pragma unroll
    for (int t2=0; t2<2; t2++){
      int col = (2*w+t2)*16 + lr;
      float g1 = l1g[col], b1 = l1b[col];
      #pragma unroll
      for (int i=0;i<4;i++){
        int row = lg*4 + i;
        float S = partS[row][0]+partS[row][1]+partS[row][2]+partS[row][3];
        float Q = partQ[row][0]+partQ[row][1]+partQ[row][2]+partQ[row][3];
        float m = S*(1.f/HH);
        float inv = 1.f/sqrtf(Q*(1.f/HH) - m*m + 1e-5f);
        float y = (vv[t2][i]-m)*inv*g1 + b1;
        yLb[row*HH + col] = y;
        hv1b[row*136 + col] = f2bf(y);  // acs already in regs; barrier passed
      }
    }
  }
  __syncthreads();

  // ---- GEMM1: [16x128]@WiT -> gelu -> ffh bf16 ----
  {
    s16x8 afr[4];
    #pragma unroll
    for (int ks=0; ks<4; ks++)
      afr[ks] = *reinterpret_cast<const s16x8*>(&hv1b[lr*136 + ks*32 + lg*8]);
    #pragma unroll
    for (int q=0; q<8; q++){
      int ncol = (w*8+q)*16 + lr;
      f32x4 C = (f32x4){0,0,0,0};
      #pragma unroll
      for (int ks=0; ks<4; ks++){
        s16x8 bv = *reinterpret_cast<const s16x8*>(&wiT[ncol*HH + ks*32 + lg*8]);
        C = __builtin_amdgcn_mfma_f32_16x16x32_bf16(afr[ks], bv, C, 0,0,0);
      }
      float bi = Wib[ncol];
      #pragma unroll
      for (int i=0;i<4;i++){
        int row = lg*4 + i;
        ffhb[row*520 + ncol] = f2bf(fgelu(C[i] + bi));
      }
    }
  }
  __syncthreads();

  // ---- GEMM2: [16x512]@WoT -> residual + LN2 ----
  f32x4 C2[2];
  C2[0]=(f32x4){0,0,0,0}; C2[1]=(f32x4){0,0,0,0};
  for (int ks=0; ks<16; ++ks){
    s16x8 a = *reinterpret_cast<const s16x8*>(&ffhb[lr*520 + ks*32 + lg*8]);
    #pragma unroll
    for (int t2=0; t2<2; t2++){
      int ncol = (2*w+t2)*16 + lr;
      s16x8 bv = *reinterpret_cast<const s16x8*>(&woT[ncol*FFD + ks*32 + lg*8]);
      C2[t2] = __builtin_amdgcn_mfma_f32_16x16x32_bf16(a, bv, C2[t2], 0,0,0);
    }
  }
  float vv[2][4];
  float ps[4] = {0,0,0,0}, pq[4] = {0,0,0,0};
  #pragma unroll
  for (int t2=0; t2<2; t2++){
    int col = (2*w+t2)*16 + lr;
    float bo = Wob[col];
    #pragma unroll
    for (int i=0;i<4;i++){
      int row = lg*4 + i;
      float v = yLb[row*HH + col] + C2[t2][i] + bo;
      vv[t2][i] = v;
      ps[i] += v; pq[i] += v*v;
    }
  }
  #pragma unroll
  for (int i=0;i<4;i++){
    #pragma unroll
    for (int o=1;o<16;o<<=1){
      ps[i] += __shfl_xor(ps[i], o, 64);
      pq[i] += __shfl_xor(pq[i], o, 64);
    }
    if (lr == 0){ partS[lg*4+i][w] = ps[i]; partQ[lg*4+i][w] = pq[i]; }
  }
  __syncthreads();
  float mean[4], inv[4];
  #pragma unroll
  for (int i=0;i<4;i++){
    int row = lg*4 + i;
    float S = partS[row][0]+partS[row][1]+partS[row][2]+partS[row][3];
    float Q = partQ[row][0]+partQ[row][1]+partQ[row][2]+partQ[row][3];
    float m = S*(1.f/HH);
    float var = Q*(1.f/HH) - m*m;
    mean[i] = m;
    inv[i] = 1.f/sqrtf(var + 1e-5f);
  }
  #pragma unroll
  for (int t2=0; t2<2; t2++){
    int col = (2*w+t2)*16 + lr;
    float g2 = l2g[col], b2 = l2b[col];
    #pragma unroll
    for (int i=0;i<4;i++){
      int row = lg*4 + i;
      out[(size_t)(base+row)*HH + col] = (vv[t2][i]-mean[i])*inv[i]*g2 + b2;
    }
  }
}

extern "C" void kernel_launch(void* const* d_in, const int* in_sizes, int n_in,
                              void* d_out, int out_size, void* d_ws, size_t ws_size,
                              hipStream_t stream) {
  (void)in_sizes; (void)n_in; (void)out_size; (void)ws_size;
  const float* X   = (const float*)d_in[0];
  const int*   Ei  = (const int*)  d_in[1];
  const float* Wv  = (const float*)d_in[2];
  const float* Wvb = (const float*)d_in[3];
  const float* We  = (const float*)d_in[4];
  const float* Web = (const float*)d_in[5];
  const float* W1  = (const float*)d_in[6];
  const float* W1b = (const float*)d_in[7];
  const float* W2  = (const float*)d_in[8];
  const float* W2b = (const float*)d_in[9];
  const float* W3  = (const float*)d_in[10];
  const float* W3b = (const float*)d_in[11];
  const float* Wi  = (const float*)d_in[12];
  const float* Wib = (const float*)d_in[13];
  const float* Wo  = (const float*)d_in[14];
  const float* Wob = (const float*)d_in[15];
  const float* l1g = (const float*)d_in[16];
  const float* l1b = (const float*)d_in[17];
  const float* l2g = (const float*)d_in[18];
  const float* l2b = (const float*)d_in[19];
  float* out = (float*)d_out;

  float* wsf    = (float*)d_ws;
  float* featws = wsf + 0;        // 172032
  float* Qws    = wsf + 172032;   // 73728
  float* hVws   = wsf + 245760;   // 1048576
  float* Gws    = wsf + 1294336;  // 1048576
  float* Sws    = wsf + 2342912;  // 1048576
  short* efB    = (short*)(wsf + 3391488);  // 8192*32*16 bf16 -> 2097152 floats
  short* wfoldT = (short*)(wsf + 5488640);  // 1024
  float* bfold  = wsf + 5489664;            // 128
  short* w2t    = (short*)(wsf + 5489792);  // 8192
  short* w1aT   = (short*)(wsf + 5497984);  // 8192
  short* w1cT   = (short*)(wsf + 5506176);  // 8192
  short* wiT    = (short*)(wsf + 5514368);  // 32768
  short* woT    = (short*)(wsf + 5547136);  // 32768
  short* w3T    = (short*)(wsf + 5579904);  // 8192 (end 5588096 ~22.4 MB)

  k_init <<<dim3(809), dim3(256), 0, stream>>>(X, Qws, featws, We, Web, W1, W2, Wi, Wo, W3,
                                               wfoldT, bfold, w2t, w1aT, w1cT, wiT, woT, w3T);
  k_ep   <<<dim3(BB*NN/ENB + BB*NN/PNB), dim3(256), 0, stream>>>(
             X, Ei, Qws, efB, featws, Wv, Wvb, w1aT, w1cT, W1b, bfold, hVws, Sws, Gws);
  k_fused<<<dim3(BB*NN/FNB), dim3(256), 0, stream>>>(
             Ei, efB, Sws, Gws, wfoldT, w2t, W2b, hVws, w3T, W3b, wiT, woT,
             Wib, Wob, l1g, l1b, l2g, l2b, out);
}